// Round 18
// baseline (90.235 us; speedup 1.0000x reference)
//
#include <hip/hip_runtime.h>
#include <hip/hip_bf16.h>

typedef __hip_bfloat16 bf16;
typedef __bf16 bf16x8 __attribute__((ext_vector_type(8)));
typedef float f32x2 __attribute__((ext_vector_type(2)));
typedef float f32x4 __attribute__((ext_vector_type(4)));
typedef float f32x16 __attribute__((ext_vector_type(16)));

#define MFMA16(a,b,c) __builtin_amdgcn_mfma_f32_16x16x32_bf16(a,b,c,0,0,0)
#define MFMA32(a,b,c) __builtin_amdgcn_mfma_f32_32x32x16_bf16(a,b,c,0,0,0)

static __device__ __forceinline__ bf16x8 ld8(const bf16* p){
  return *reinterpret_cast<const bf16x8*>(p);
}
static __device__ __forceinline__ unsigned pk(float a, float b){
  __hip_bfloat162 h = __float22bfloat162_rn(make_float2(a, b));
  return *reinterpret_cast<unsigned*>(&h);
}

#define GLL(src, dst) __builtin_amdgcn_global_load_lds( \
    (const __attribute__((address_space(1))) unsigned int*)(src), \
    (__attribute__((address_space(3))) unsigned int*)(dst), 16, 0, 0)

// ---- merged: weight conversion (blocks 0..767) + groupnorm partial sums (768..1279) ----
__global__ void k_wgs1(const float* __restrict__ qw, const float* __restrict__ pw,
                       bf16* __restrict__ qwb, bf16* __restrict__ pwb,
                       const float* __restrict__ x, float* __restrict__ gpart){
  int bx = blockIdx.x;
  int tid = threadIdx.x;
  if (bx < 768){
    int i = bx*256 + tid;
    int o = i >> 8;
    int j = o % 192;
    float f = (j < 64) ? 0.51006973f           // 0.35355339 * log2(e)
            : (j < 128) ? 0.35355339f : 1.0f;
    qwb[i] = __float2bfloat16(qw[i]*f);
    if (i < 256*256) pwb[i] = __float2bfloat16(pw[i]);
    return;
  }
  int idx = bx - 768;             // 0..511
  int glin = idx >> 3;            // 0..63 = b*32+g
  int s = idx & 7;                // slice
  const float* xb = x + (size_t)glin*8*4096 + s*512;
  const float* p = xb + (size_t)(tid>>5)*4096 + (tid&31)*16;
  float s1 = 0.f, s2 = 0.f;
  #pragma unroll
  for (int i = 0; i < 4; i++){
    float4 v = *(const float4*)(p + i*4);
    s1 += (v.x+v.y)+(v.z+v.w);
    s2 += (v.x*v.x+v.y*v.y)+(v.z*v.z+v.w*v.w);
  }
  #pragma unroll
  for (int d = 1; d < 64; d <<= 1){ s1 += __shfl_xor(s1,d); s2 += __shfl_xor(s2,d); }
  __shared__ float r1[4], r2[4];
  int w = tid >> 6;
  if ((tid & 63) == 0){ r1[w] = s1; r2[w] = s2; }
  __syncthreads();
  if (tid == 0){
    gpart[(glin*8+s)*2+0] = (r1[0]+r1[1])+(r1[2]+r1[3]);
    gpart[(glin*8+s)*2+1] = (r2[0]+r2[1])+(r2[2]+r2[3]);
  }
}

// ---- fused groupnorm-apply + qkv GEMM.
//      grid (128 t-tiles of 32, 2 b), 512 thr.  xn tile lives only in LDS.
//      q: [bh][t][64].  K,V stored FRAGMENT-LINEAR for attn. ----
__global__ __launch_bounds__(512,2) void k_gqkv(const float* __restrict__ x,
      const float* __restrict__ gpart, const float* __restrict__ nw,
      const float* __restrict__ nb, const bf16* __restrict__ wb,
      bf16* __restrict__ q, bf16* __restrict__ k, bf16* __restrict__ v){
  int t0 = blockIdx.x * 32;
  int b  = blockIdx.y;
  int tid = threadIdx.x;
  __shared__ bf16 tcm[256][36];     // c-major staging, 72B row stride
  __shared__ bf16 tlB[32][264];     // t-major B-operand tile, 528B row stride
  __shared__ float2 scb[256];

  if (tid < 256){
    int c = tid;
    int glin = b*32 + (c>>3);
    float s1=0.f, s2=0.f;
    #pragma unroll
    for (int s=0;s<8;s++){ s1+=gpart[(glin*8+s)*2]; s2+=gpart[(glin*8+s)*2+1]; }
    float mean = s1*(1.f/32768.f);
    float var = s2*(1.f/32768.f)-mean*mean;
    float rstd = rsqrtf(var+1e-5f);
    float sc = nw[c]*rstd;
    scb[c] = make_float2(sc, nb[c]-mean*sc);
  }
  __syncthreads();
  {
    int c = tid>>1, half = tid&1;
    float2 sb = scb[c];
    const float* xr = x + ((size_t)(b*256+c))*4096 + t0 + half*16;
    #pragma unroll
    for (int j=0;j<4;j++){
      float4 vv = *(const float4*)(xr + j*4);
      uint2 uu;
      uu.x = pk(vv.x*sb.x+sb.y, vv.y*sb.x+sb.y);
      uu.y = pk(vv.z*sb.x+sb.y, vv.w*sb.x+sb.y);
      *(uint2*)&tcm[c][half*16 + j*4] = uu;
    }
  }
  __syncthreads();
  #pragma unroll
  for (int pass=0; pass<2; ++pass){
    int idx = tid + pass*512;        // 0..1023: t (0..31) x c8 (0..31)
    int t = idx >> 5, c8 = idx & 31;
    unsigned short us[8];
    #pragma unroll
    for (int j=0;j<8;j++) us[j] = *(unsigned short*)&tcm[c8*8+j][t];
    uint4 o;
    o.x = us[0]|((unsigned)us[1]<<16); o.y = us[2]|((unsigned)us[3]<<16);
    o.z = us[4]|((unsigned)us[5]<<16); o.w = us[6]|((unsigned)us[7]<<16);
    *(uint4*)&tlB[t][c8*8] = o;
  }
  __syncthreads();

  int w = tid>>6, L = tid&63, l15 = L&15, lg = L>>4;
  f32x4 acc[6][2] = {};
  const bf16* arow = wb + (size_t)(w*96 + l15)*256 + lg*8;
  #pragma unroll
  for (int kk=0;kk<8;kk++){
    bf16x8 bbf[2];
    #pragma unroll
    for (int n=0;n<2;n++) bbf[n] = ld8(&tlB[n*16+l15][kk*32 + lg*8]);
    #pragma unroll
    for (int ot=0;ot<6;ot++){
      bf16x8 a = ld8(arow + (size_t)ot*16*256 + kk*32);
      #pragma unroll
      for (int n=0;n<2;n++) acc[ot][n] = MFMA16(a, bbf[n], acc[ot][n]);
    }
  }
  #pragma unroll
  for (int ot=0;ot<6;ot++){
    #pragma unroll
    for (int n=0;n<2;n++){
      int t = t0 + n*16 + l15;
      #pragma unroll
      for (int i=0;i<4;i++){
        int o = w*96 + ot*16 + lg*4 + i;
        int hh = o/192, j = o%192;
        int bh = b*4 + hh;
        bf16 val = __float2bfloat16(acc[ot][n][i]);
        if (j<64){
          q[((size_t)bh*4096+t)*64+j] = val;
        } else if (j<128){
          int kc = j-64;
          k[((size_t)((bh*128 + (t>>5))*4 + (kc>>4)))*512
            + ((t&31) + ((kc>>3)&1)*32)*8 + (kc&7)] = val;
        } else {
          int vc = j-128;
          v[((size_t)((bh*256 + (t>>4))*2 + (vc>>5)))*512
            + ((vc&31) + ((t>>3)&1)*32)*8 + (t&7)] = val;
        }
      }
    }
  }
}

// ---- flash attention v13 (r16 best config): 512 thr, 8 waves share 64-s
//      tiles, 3-buf LDS, counted vmcnt, CIN C-init, fragment-linear K/V,
//      no setprio, ssplit=4. ----
__global__ __launch_bounds__(512,2) void k_attn(const bf16* __restrict__ q,
      const char* __restrict__ kg_, const char* __restrict__ vg_,
      char* __restrict__ opart, float* __restrict__ lsumP, int ssplit){
  const int bh = blockIdx.x;
  const int qg = blockIdx.y * 256;
  const int z  = blockIdx.z;
  const int slen = 4096 / ssplit;
  const int niters = slen >> 6;
  const int s_begin = z * slen;
  const int tid = threadIdx.x;
  const int w = tid >> 6, L = tid & 63, l31 = L & 31, hi = L >> 5;

  __shared__ __align__(16) char kb[3][8192];
  __shared__ __align__(16) char vb[3][8192];

  bf16x8 qf[4];
  {
    const bf16* qr = q + (size_t)bh*4096*64 + (size_t)(qg + w*32 + l31)*64 + hi*8;
    #pragma unroll
    for (int ch = 0; ch < 4; ch++)
      qf[ch] = ld8(qr + ch*16);
  }

  const char* kg = kg_ + ((size_t)bh<<19);
  const char* vg = vg_ + ((size_t)bh<<19);

  // wave w stages 1 K-chunk + 1 V-chunk per tile
  #define STAGE(buf, t) do { \
    int ss = s_begin + (t)*64; \
    GLL(kg + (size_t)((ss>>5) + (w>>2))*4096 + (w&3)*1024 + L*16, (char*)&kb[buf][0] + w*1024); \
    GLL(vg + (size_t)((ss>>4) + (w>>1))*2048 + (w&1)*1024 + L*16, (char*)&vb[buf][0] + w*1024); \
  } while(0)

  STAGE(0, 0);
  STAGE(1, 1);
  f32x16 oaccT[2] = {};
  f32x2 lsum2 = {0.f, 0.f};
  const float NSH = -11.5415603f;     // -8*log2(e); exp(S-8) = exp2(acc) via C-init
  f32x16 CIN;
  #pragma unroll
  for (int r = 0; r < 16; ++r) CIN[r] = NSH;
  int cur = 0, n2 = 2;

  for (int t = 0; t < niters; ++t){
    if (t < niters-1) asm volatile("s_waitcnt vmcnt(2)" ::: "memory");
    else              asm volatile("s_waitcnt vmcnt(0)" ::: "memory");
    __builtin_amdgcn_s_barrier();
    if (t + 2 < niters) STAGE(n2, t+2);

    const char* kc = &kb[cur][0];
    const char* vc = &vb[cur][0];
    #pragma unroll
    for (int sc2 = 0; sc2 < 2; ++sc2){
      bf16x8 kf[4];
      #pragma unroll
      for (int ch = 0; ch < 4; ++ch)
        kf[ch] = *(const bf16x8*)(kc + (sc2*4 + ch)*1024 + L*16);
      f32x16 sacc = MFMA32(kf[0], qf[0], CIN);   // D != C: reads persistent CIN
      #pragma unroll
      for (int ch = 1; ch < 4; ++ch)
        sacc = MFMA32(kf[ch], qf[ch], sacc);
      #pragma unroll
      for (int sc = 0; sc < 2; ++sc){
        float p0 = __builtin_amdgcn_exp2f(sacc[sc*8+0]);
        float p1 = __builtin_amdgcn_exp2f(sacc[sc*8+1]);
        float p2 = __builtin_amdgcn_exp2f(sacc[sc*8+2]);
        float p3 = __builtin_amdgcn_exp2f(sacc[sc*8+3]);
        float p4 = __builtin_amdgcn_exp2f(sacc[sc*8+4]);
        float p5 = __builtin_amdgcn_exp2f(sacc[sc*8+5]);
        float p6 = __builtin_amdgcn_exp2f(sacc[sc*8+6]);
        float p7 = __builtin_amdgcn_exp2f(sacc[sc*8+7]);
        f32x2 e0 = {p0, p1}, e1 = {p2, p3}, e2 = {p4, p5}, e3 = {p6, p7};
        lsum2 += (e0 + e1) + (e2 + e3);
        unsigned pa0 = pk(p0, p1);
        unsigned pa1 = pk(p2, p3);
        unsigned pb0 = pk(p4, p5);
        unsigned pb1 = pk(p6, p7);
        asm("v_permlane32_swap_b32 %0, %1" : "+v"(pa0), "+v"(pb0));
        asm("v_permlane32_swap_b32 %0, %1" : "+v"(pa1), "+v"(pb1));
        union { unsigned u[4]; bf16x8 v; } pu;
        pu.u[0]=pa0; pu.u[1]=pa1; pu.u[2]=pb0; pu.u[3]=pb1;
        bf16x8 vfa = *(const bf16x8*)(vc + ((sc2*2+sc)*2 + 0)*1024 + L*16);
        bf16x8 vfb = *(const bf16x8*)(vc + ((sc2*2+sc)*2 + 1)*1024 + L*16);
        oaccT[0] = MFMA32(vfa, pu.v, oaccT[0]);
        oaccT[1] = MFMA32(vfb, pu.v, oaccT[1]);
      }
    }
    cur = (cur==2)?0:cur+1;
    n2  = (n2==2)?0:n2+1;
  }
  #undef STAGE

  char* ob = opart + (size_t)(bh*ssplit + z)*4096*128;
  {
    float ls = lsum2[0] + lsum2[1];
    ls += __shfl_xor(ls, 32);
    int qrow = qg + w*32 + l31;
    if (hi == 0) lsumP[(size_t)(bh*ssplit+z)*4096 + qrow] = ls;
    #pragma unroll
    for (int ct = 0; ct < 2; ++ct)
      #pragma unroll
      for (int b2 = 0; b2 < 4; ++b2){
        unsigned w0 = pk(oaccT[ct][b2*4+0], oaccT[ct][b2*4+1]);
        unsigned w1 = pk(oaccT[ct][b2*4+2], oaccT[ct][b2*4+3]);
        uint2 val; val.x = w0; val.y = w1;
        *(uint2*)(ob + (size_t)qrow*128 + (ct*32 + b2*8 + hi*4)*2) = val;
      }
  }
}

// ---- fused combine + proj GEMM + bias + residual.  512 thr (8 waves),
//      16-row t-tiles, grid (256, 2) = 512 blocks = 2 blocks/CU. ----
__global__ __launch_bounds__(512,2) void k_oproj(const char* __restrict__ opart,
                        const float* __restrict__ lsumP,
                        const bf16* __restrict__ pwb, const float* __restrict__ pb,
                        const float* __restrict__ x, float* __restrict__ out, int ssplit){
  int t0 = blockIdx.x * 16;
  int b  = blockIdx.y;
  int tid = threadIdx.x;
  __shared__ bf16 tl[16][280];    // stride 280 elem = 35 slots (odd mod 8): bank-partitioned

  // combine phase: 512 thr = 16 rows x 32 c-octets, 1 task each
  {
    int rrow = tid >> 5;          // 0..15
    int c8 = tid & 31;            // 0..31 -> channels c8*8..c8*8+7
    int h = c8 >> 3;              // head 0..3
    int chh = (c8 & 7) * 8;       // channel-in-head offset
    int bh = b*4 + h;
    int qrow = t0 + rrow;
    float l = 0.f, o[8] = {};
    for (int z = 0; z < ssplit; ++z){
      size_t base = (size_t)(bh*ssplit + z)*4096 + qrow;
      l += lsumP[base];
      uint4 u = *(const uint4*)(opart + base*128 + chh*2);
      unsigned uu[4] = {u.x, u.y, u.z, u.w};
      #pragma unroll
      for (int j = 0; j < 4; ++j){
        unsigned lobits = (uu[j] & 0xffffu) << 16;
        unsigned hibits = uu[j] & 0xffff0000u;
        o[2*j]   += *reinterpret_cast<float*>(&lobits);
        o[2*j+1] += *reinterpret_cast<float*>(&hibits);
      }
    }
    float inv = 1.f / l;
    uint4 wv;
    wv.x = pk(o[0]*inv, o[1]*inv); wv.y = pk(o[2]*inv, o[3]*inv);
    wv.z = pk(o[4]*inv, o[5]*inv); wv.w = pk(o[6]*inv, o[7]*inv);
    *(uint4*)&tl[rrow][c8*8] = wv;
  }
  __syncthreads();

  // GEMM: 8 waves x 32 o-rows x 16 t-cols
  int w = tid >> 6, L = tid & 63, l15 = L & 15, lg = L >> 4;
  f32x4 acc[2] = {};
  const bf16* arow = pwb + (size_t)(w*32 + l15)*256 + lg*8;
  #pragma unroll
  for (int kk = 0; kk < 8; kk++){
    bf16x8 bb = ld8(&tl[l15][kk*32 + lg*8]);
    #pragma unroll
    for (int i = 0; i < 2; i++){
      bf16x8 a = ld8(arow + i*16*256 + kk*32);
      acc[i] = MFMA16(a, bb, acc[i]);
    }
  }
  #pragma unroll
  for (int i = 0; i < 2; i++){
    #pragma unroll
    for (int ii = 0; ii < 4; ii++){
      int o = w*32 + i*16 + lg*4 + ii;
      float bias = pb[o];
      const float* xr = x + ((size_t)(b*256 + o))*4096 + t0;
      float* orow = out + ((size_t)(b*256 + o))*4096 + t0;
      int tt = l15;
      orow[tt] = acc[i][ii] + bias + xr[tt];
    }
  }
}

extern "C" void kernel_launch(void* const* d_in, const int* in_sizes, int n_in,
                              void* d_out, int out_size, void* d_ws, size_t ws_size,
                              hipStream_t stream){
  const float* x     = (const float*)d_in[0];
  const float* nw    = (const float*)d_in[1];
  const float* nb    = (const float*)d_in[2];
  const float* qkvw  = (const float*)d_in[3];
  const float* projw = (const float*)d_in[4];
  const float* projb = (const float*)d_in[5];
  float* out = (float*)d_out;
  char* ws = (char*)d_ws;
  bf16* qwb   = (bf16*)(ws);                                  // 384 KB
  bf16* pwb   = (bf16*)(ws + 393216);                         // 128 KB
  bf16* q     = (bf16*)(ws + 524288);                         // 4 MB
  char* kk    = (ws + 524288 + 4194304);                      // 4 MB (fragment-linear)
  char* v     = (ws + 524288 + 2*4194304);                    // 4 MB (fragment-linear)
  size_t off_opart = 524288 + (size_t)3*4194304;
  const int ssplit = 4;            // attn grid 8x16x4 = 512 blocks = 2/CU
  char*  opart = ws + off_opart;   // 16 MB
  size_t off_lsum  = off_opart + (size_t)8*ssplit*4096*128;
  float* lsum  = (float*)(ws + off_lsum);                     // 512 KB
  size_t off_gpart = off_lsum + (size_t)8*ssplit*4096*4;
  float* gpart = (float*)(ws + off_gpart);

  k_wgs1<<<1280, 256, 0, stream>>>(qkvw, projw, qwb, pwb, x, gpart);
  k_gqkv<<<dim3(128,2), 512, 0, stream>>>(x, gpart, nw, nb, qwb, q, (bf16*)kk, (bf16*)v);
  k_attn<<<dim3(8,16,ssplit), 512, 0, stream>>>(q, kk, v, opart, lsum, ssplit);
  k_oproj<<<dim3(256,2), 512, 0, stream>>>(opart, lsum, pwb, projb, x, out, ssplit);
}

// Round 19
// 87.082 us; speedup vs baseline: 1.0362x; 1.0362x over previous
//
#include <hip/hip_runtime.h>
#include <hip/hip_bf16.h>

typedef __hip_bfloat16 bf16;
typedef __bf16 bf16x8 __attribute__((ext_vector_type(8)));
typedef float f32x2 __attribute__((ext_vector_type(2)));
typedef float f32x4 __attribute__((ext_vector_type(4)));
typedef float f32x16 __attribute__((ext_vector_type(16)));

#define MFMA16(a,b,c) __builtin_amdgcn_mfma_f32_16x16x32_bf16(a,b,c,0,0,0)
#define MFMA32(a,b,c) __builtin_amdgcn_mfma_f32_32x32x16_bf16(a,b,c,0,0,0)

static __device__ __forceinline__ bf16x8 ld8(const bf16* p){
  return *reinterpret_cast<const bf16x8*>(p);
}
static __device__ __forceinline__ unsigned pk(float a, float b){
  __hip_bfloat162 h = __float22bfloat162_rn(make_float2(a, b));
  return *reinterpret_cast<unsigned*>(&h);
}

#define GLL(src, dst) __builtin_amdgcn_global_load_lds( \
    (const __attribute__((address_space(1))) unsigned int*)(src), \
    (__attribute__((address_space(3))) unsigned int*)(dst), 16, 0, 0)

// ---- merged: weight conversion (blocks 0..767) + groupnorm partial sums (768..1279) ----
__global__ void k_wgs1(const float* __restrict__ qw, const float* __restrict__ pw,
                       bf16* __restrict__ qwb, bf16* __restrict__ pwb,
                       const float* __restrict__ x, float* __restrict__ gpart){
  int bx = blockIdx.x;
  int tid = threadIdx.x;
  if (bx < 768){
    int i = bx*256 + tid;
    int o = i >> 8;
    int j = o % 192;
    float f = (j < 64) ? 0.51006973f           // 0.35355339 * log2(e)
            : (j < 128) ? 0.35355339f : 1.0f;
    qwb[i] = __float2bfloat16(qw[i]*f);
    if (i < 256*256) pwb[i] = __float2bfloat16(pw[i]);
    return;
  }
  int idx = bx - 768;             // 0..511
  int glin = idx >> 3;            // 0..63 = b*32+g
  int s = idx & 7;                // slice
  const float* xb = x + (size_t)glin*8*4096 + s*512;
  const float* p = xb + (size_t)(tid>>5)*4096 + (tid&31)*16;
  float s1 = 0.f, s2 = 0.f;
  #pragma unroll
  for (int i = 0; i < 4; i++){
    float4 v = *(const float4*)(p + i*4);
    s1 += (v.x+v.y)+(v.z+v.w);
    s2 += (v.x*v.x+v.y*v.y)+(v.z*v.z+v.w*v.w);
  }
  #pragma unroll
  for (int d = 1; d < 64; d <<= 1){ s1 += __shfl_xor(s1,d); s2 += __shfl_xor(s2,d); }
  __shared__ float r1[4], r2[4];
  int w = tid >> 6;
  if ((tid & 63) == 0){ r1[w] = s1; r2[w] = s2; }
  __syncthreads();
  if (tid == 0){
    gpart[(glin*8+s)*2+0] = (r1[0]+r1[1])+(r1[2]+r1[3]);
    gpart[(glin*8+s)*2+1] = (r2[0]+r2[1])+(r2[2]+r2[3]);
  }
}

// ---- fused groupnorm-apply + qkv GEMM.
//      grid (128 t-tiles of 32, 2 b), 512 thr.  xn tile lives only in LDS.
//      q: [bh][t][64].  K,V stored FRAGMENT-LINEAR for attn. ----
__global__ __launch_bounds__(512,2) void k_gqkv(const float* __restrict__ x,
      const float* __restrict__ gpart, const float* __restrict__ nw,
      const float* __restrict__ nb, const bf16* __restrict__ wb,
      bf16* __restrict__ q, bf16* __restrict__ k, bf16* __restrict__ v){
  int t0 = blockIdx.x * 32;
  int b  = blockIdx.y;
  int tid = threadIdx.x;
  __shared__ bf16 tcm[256][36];     // c-major staging, 72B row stride
  __shared__ bf16 tlB[32][264];     // t-major B-operand tile, 528B row stride
  __shared__ float2 scb[256];

  if (tid < 256){
    int c = tid;
    int glin = b*32 + (c>>3);
    float s1=0.f, s2=0.f;
    #pragma unroll
    for (int s=0;s<8;s++){ s1+=gpart[(glin*8+s)*2]; s2+=gpart[(glin*8+s)*2+1]; }
    float mean = s1*(1.f/32768.f);
    float var = s2*(1.f/32768.f)-mean*mean;
    float rstd = rsqrtf(var+1e-5f);
    float sc = nw[c]*rstd;
    scb[c] = make_float2(sc, nb[c]-mean*sc);
  }
  __syncthreads();
  {
    int c = tid>>1, half = tid&1;
    float2 sb = scb[c];
    const float* xr = x + ((size_t)(b*256+c))*4096 + t0 + half*16;
    #pragma unroll
    for (int j=0;j<4;j++){
      float4 vv = *(const float4*)(xr + j*4);
      uint2 uu;
      uu.x = pk(vv.x*sb.x+sb.y, vv.y*sb.x+sb.y);
      uu.y = pk(vv.z*sb.x+sb.y, vv.w*sb.x+sb.y);
      *(uint2*)&tcm[c][half*16 + j*4] = uu;
    }
  }
  __syncthreads();
  #pragma unroll
  for (int pass=0; pass<2; ++pass){
    int idx = tid + pass*512;        // 0..1023: t (0..31) x c8 (0..31)
    int t = idx >> 5, c8 = idx & 31;
    unsigned short us[8];
    #pragma unroll
    for (int j=0;j<8;j++) us[j] = *(unsigned short*)&tcm[c8*8+j][t];
    uint4 o;
    o.x = us[0]|((unsigned)us[1]<<16); o.y = us[2]|((unsigned)us[3]<<16);
    o.z = us[4]|((unsigned)us[5]<<16); o.w = us[6]|((unsigned)us[7]<<16);
    *(uint4*)&tlB[t][c8*8] = o;
  }
  __syncthreads();

  int w = tid>>6, L = tid&63, l15 = L&15, lg = L>>4;
  f32x4 acc[6][2] = {};
  const bf16* arow = wb + (size_t)(w*96 + l15)*256 + lg*8;
  #pragma unroll
  for (int kk=0;kk<8;kk++){
    bf16x8 bbf[2];
    #pragma unroll
    for (int n=0;n<2;n++) bbf[n] = ld8(&tlB[n*16+l15][kk*32 + lg*8]);
    #pragma unroll
    for (int ot=0;ot<6;ot++){
      bf16x8 a = ld8(arow + (size_t)ot*16*256 + kk*32);
      #pragma unroll
      for (int n=0;n<2;n++) acc[ot][n] = MFMA16(a, bbf[n], acc[ot][n]);
    }
  }
  #pragma unroll
  for (int ot=0;ot<6;ot++){
    #pragma unroll
    for (int n=0;n<2;n++){
      int t = t0 + n*16 + l15;
      #pragma unroll
      for (int i=0;i<4;i++){
        int o = w*96 + ot*16 + lg*4 + i;
        int hh = o/192, j = o%192;
        int bh = b*4 + hh;
        bf16 val = __float2bfloat16(acc[ot][n][i]);
        if (j<64){
          q[((size_t)bh*4096+t)*64+j] = val;
        } else if (j<128){
          int kc = j-64;
          k[((size_t)((bh*128 + (t>>5))*4 + (kc>>4)))*512
            + ((t&31) + ((kc>>3)&1)*32)*8 + (kc&7)] = val;
        } else {
          int vc = j-128;
          v[((size_t)((bh*256 + (t>>4))*2 + (vc>>5)))*512
            + ((vc&31) + ((t>>3)&1)*32)*8 + (t&7)] = val;
        }
      }
    }
  }
}

// ---- flash attention v13 (best measured config): 512 thr, 8 waves share
//      64-s tiles, 3-buf LDS, counted vmcnt, CIN C-init, fragment-linear
//      K/V (conflict-free), no setprio, ssplit=4. ----
__global__ __launch_bounds__(512,2) void k_attn(const bf16* __restrict__ q,
      const char* __restrict__ kg_, const char* __restrict__ vg_,
      char* __restrict__ opart, float* __restrict__ lsumP, int ssplit){
  const int bh = blockIdx.x;
  const int qg = blockIdx.y * 256;
  const int z  = blockIdx.z;
  const int slen = 4096 / ssplit;
  const int niters = slen >> 6;
  const int s_begin = z * slen;
  const int tid = threadIdx.x;
  const int w = tid >> 6, L = tid & 63, l31 = L & 31, hi = L >> 5;

  __shared__ __align__(16) char kb[3][8192];
  __shared__ __align__(16) char vb[3][8192];

  bf16x8 qf[4];
  {
    const bf16* qr = q + (size_t)bh*4096*64 + (size_t)(qg + w*32 + l31)*64 + hi*8;
    #pragma unroll
    for (int ch = 0; ch < 4; ch++)
      qf[ch] = ld8(qr + ch*16);
  }

  const char* kg = kg_ + ((size_t)bh<<19);
  const char* vg = vg_ + ((size_t)bh<<19);

  // wave w stages 1 K-chunk + 1 V-chunk per tile
  #define STAGE(buf, t) do { \
    int ss = s_begin + (t)*64; \
    GLL(kg + (size_t)((ss>>5) + (w>>2))*4096 + (w&3)*1024 + L*16, (char*)&kb[buf][0] + w*1024); \
    GLL(vg + (size_t)((ss>>4) + (w>>1))*2048 + (w&1)*1024 + L*16, (char*)&vb[buf][0] + w*1024); \
  } while(0)

  STAGE(0, 0);
  STAGE(1, 1);
  f32x16 oaccT[2] = {};
  f32x2 lsum2 = {0.f, 0.f};
  const float NSH = -11.5415603f;     // -8*log2(e); exp(S-8) = exp2(acc) via C-init
  f32x16 CIN;
  #pragma unroll
  for (int r = 0; r < 16; ++r) CIN[r] = NSH;
  int cur = 0, n2 = 2;

  for (int t = 0; t < niters; ++t){
    if (t < niters-1) asm volatile("s_waitcnt vmcnt(2)" ::: "memory");
    else              asm volatile("s_waitcnt vmcnt(0)" ::: "memory");
    __builtin_amdgcn_s_barrier();
    if (t + 2 < niters) STAGE(n2, t+2);

    const char* kc = &kb[cur][0];
    const char* vc = &vb[cur][0];
    #pragma unroll
    for (int sc2 = 0; sc2 < 2; ++sc2){
      bf16x8 kf[4];
      #pragma unroll
      for (int ch = 0; ch < 4; ++ch)
        kf[ch] = *(const bf16x8*)(kc + (sc2*4 + ch)*1024 + L*16);
      f32x16 sacc = MFMA32(kf[0], qf[0], CIN);   // D != C: reads persistent CIN
      #pragma unroll
      for (int ch = 1; ch < 4; ++ch)
        sacc = MFMA32(kf[ch], qf[ch], sacc);
      #pragma unroll
      for (int sc = 0; sc < 2; ++sc){
        float p0 = __builtin_amdgcn_exp2f(sacc[sc*8+0]);
        float p1 = __builtin_amdgcn_exp2f(sacc[sc*8+1]);
        float p2 = __builtin_amdgcn_exp2f(sacc[sc*8+2]);
        float p3 = __builtin_amdgcn_exp2f(sacc[sc*8+3]);
        float p4 = __builtin_amdgcn_exp2f(sacc[sc*8+4]);
        float p5 = __builtin_amdgcn_exp2f(sacc[sc*8+5]);
        float p6 = __builtin_amdgcn_exp2f(sacc[sc*8+6]);
        float p7 = __builtin_amdgcn_exp2f(sacc[sc*8+7]);
        f32x2 e0 = {p0, p1}, e1 = {p2, p3}, e2 = {p4, p5}, e3 = {p6, p7};
        lsum2 += (e0 + e1) + (e2 + e3);
        unsigned pa0 = pk(p0, p1);
        unsigned pa1 = pk(p2, p3);
        unsigned pb0 = pk(p4, p5);
        unsigned pb1 = pk(p6, p7);
        asm("v_permlane32_swap_b32 %0, %1" : "+v"(pa0), "+v"(pb0));
        asm("v_permlane32_swap_b32 %0, %1" : "+v"(pa1), "+v"(pb1));
        union { unsigned u[4]; bf16x8 v; } pu;
        pu.u[0]=pa0; pu.u[1]=pa1; pu.u[2]=pb0; pu.u[3]=pb1;
        bf16x8 vfa = *(const bf16x8*)(vc + ((sc2*2+sc)*2 + 0)*1024 + L*16);
        bf16x8 vfb = *(const bf16x8*)(vc + ((sc2*2+sc)*2 + 1)*1024 + L*16);
        oaccT[0] = MFMA32(vfa, pu.v, oaccT[0]);
        oaccT[1] = MFMA32(vfb, pu.v, oaccT[1]);
      }
    }
    cur = (cur==2)?0:cur+1;
    n2  = (n2==2)?0:n2+1;
  }
  #undef STAGE

  char* ob = opart + (size_t)(bh*ssplit + z)*4096*128;
  {
    float ls = lsum2[0] + lsum2[1];
    ls += __shfl_xor(ls, 32);
    int qrow = qg + w*32 + l31;
    if (hi == 0) lsumP[(size_t)(bh*ssplit+z)*4096 + qrow] = ls;
    #pragma unroll
    for (int ct = 0; ct < 2; ++ct)
      #pragma unroll
      for (int b2 = 0; b2 < 4; ++b2){
        unsigned w0 = pk(oaccT[ct][b2*4+0], oaccT[ct][b2*4+1]);
        unsigned w1 = pk(oaccT[ct][b2*4+2], oaccT[ct][b2*4+3]);
        uint2 val; val.x = w0; val.y = w1;
        *(uint2*)(ob + (size_t)qrow*128 + (ct*32 + b2*8 + hi*4)*2) = val;
      }
  }
}

// ---- fused combine + proj GEMM + bias + residual.  512 thr (8 waves),
//      32-row t-tiles, grid (128, 2) = 256 blocks (r16 best config). ----
__global__ __launch_bounds__(512,2) void k_oproj(const char* __restrict__ opart,
                        const float* __restrict__ lsumP,
                        const bf16* __restrict__ pwb, const float* __restrict__ pb,
                        const float* __restrict__ x, float* __restrict__ out, int ssplit){
  int t0 = blockIdx.x * 32;
  int b  = blockIdx.y;
  int tid = threadIdx.x;
  __shared__ bf16 tl[32][280];    // stride 280 elem = 35 slots (odd mod 8): bank-partitioned

  // combine phase: 512 thr, each handles 2 h's
  {
    int half = tid >> 8;          // 0..1
    int t8 = tid & 255;
    int rrow = t8 >> 3;           // 0..31
    int cs = (t8 & 7) * 8;
    #pragma unroll
    for (int h2 = 0; h2 < 2; ++h2){
      int h = half*2 + h2;
      int bh = b*4 + h;
      int qrow = t0 + rrow;
      float l = 0.f, o[8] = {};
      for (int z = 0; z < ssplit; ++z){
        size_t base = (size_t)(bh*ssplit + z)*4096 + qrow;
        l += lsumP[base];
        uint4 u = *(const uint4*)(opart + base*128 + cs*2);
        unsigned uu[4] = {u.x, u.y, u.z, u.w};
        #pragma unroll
        for (int j = 0; j < 4; ++j){
          unsigned lobits = (uu[j] & 0xffffu) << 16;
          unsigned hibits = uu[j] & 0xffff0000u;
          o[2*j]   += *reinterpret_cast<float*>(&lobits);
          o[2*j+1] += *reinterpret_cast<float*>(&hibits);
        }
      }
      float inv = 1.f / l;
      uint4 wv;
      wv.x = pk(o[0]*inv, o[1]*inv); wv.y = pk(o[2]*inv, o[3]*inv);
      wv.z = pk(o[4]*inv, o[5]*inv); wv.w = pk(o[6]*inv, o[7]*inv);
      *(uint4*)&tl[rrow][h*64 + cs] = wv;
    }
  }
  __syncthreads();

  // GEMM: 8 waves x 32 o-rows
  int w = tid >> 6, L = tid & 63, l15 = L & 15, lg = L >> 4;
  f32x4 acc[2][2] = {};
  const bf16* arow = pwb + (size_t)(w*32 + l15)*256 + lg*8;
  #pragma unroll
  for (int kk = 0; kk < 8; kk++){
    bf16x8 a[2];
    #pragma unroll
    for (int i = 0; i < 2; i++) a[i] = ld8(arow + i*16*256 + kk*32);
    bf16x8 bb[2];
    #pragma unroll
    for (int n = 0; n < 2; n++) bb[n] = ld8(&tl[n*16 + l15][kk*32 + lg*8]);
    #pragma unroll
    for (int i = 0; i < 2; i++)
      #pragma unroll
      for (int n = 0; n < 2; n++)
        acc[i][n] = MFMA16(a[i], bb[n], acc[i][n]);
  }
  #pragma unroll
  for (int i = 0; i < 2; i++){
    #pragma unroll
    for (int ii = 0; ii < 4; ii++){
      int o = w*32 + i*16 + lg*4 + ii;
      float bias = pb[o];
      const float* xr = x + ((size_t)(b*256 + o))*4096 + t0;
      float* orow = out + ((size_t)(b*256 + o))*4096 + t0;
      #pragma unroll
      for (int n = 0; n < 2; n++){
        int tt = n*16 + l15;
        orow[tt] = acc[i][n][ii] + bias + xr[tt];
      }
    }
  }
}

extern "C" void kernel_launch(void* const* d_in, const int* in_sizes, int n_in,
                              void* d_out, int out_size, void* d_ws, size_t ws_size,
                              hipStream_t stream){
  const float* x     = (const float*)d_in[0];
  const float* nw    = (const float*)d_in[1];
  const float* nb    = (const float*)d_in[2];
  const float* qkvw  = (const float*)d_in[3];
  const float* projw = (const float*)d_in[4];
  const float* projb = (const float*)d_in[5];
  float* out = (float*)d_out;
  char* ws = (char*)d_ws;
  bf16* qwb   = (bf16*)(ws);                                  // 384 KB
  bf16* pwb   = (bf16*)(ws + 393216);                         // 128 KB
  bf16* q     = (bf16*)(ws + 524288);                         // 4 MB
  char* kk    = (ws + 524288 + 4194304);                      // 4 MB (fragment-linear)
  char* v     = (ws + 524288 + 2*4194304);                    // 4 MB (fragment-linear)
  size_t off_opart = 524288 + (size_t)3*4194304;
  const int ssplit = 4;            // attn grid 8x16x4 = 512 blocks = 2/CU
  char*  opart = ws + off_opart;   // 16 MB
  size_t off_lsum  = off_opart + (size_t)8*ssplit*4096*128;
  float* lsum  = (float*)(ws + off_lsum);                     // 512 KB
  size_t off_gpart = off_lsum + (size_t)8*ssplit*4096*4;
  float* gpart = (float*)(ws + off_gpart);

  k_wgs1<<<1280, 256, 0, stream>>>(qkvw, projw, qwb, pwb, x, gpart);
  k_gqkv<<<dim3(128,2), 512, 0, stream>>>(x, gpart, nw, nb, qwb, q, (bf16*)kk, (bf16*)v);
  k_attn<<<dim3(8,16,ssplit), 512, 0, stream>>>(q, kk, v, opart, lsum, ssplit);
  k_oproj<<<dim3(128,2), 512, 0, stream>>>(opart, lsum, pwb, projb, x, out, ssplit);
}